// Round 13
// baseline (119.492 us; speedup 1.0000x reference)
//
#include <hip/hip_runtime.h>
#include <hip/hip_bf16.h>

#define N_ROWS 300000
#define FIN    128
#define HDIM   64
#define ODIM   32
#define KREL   5
#define BR     64
#define NTILES ((N_ROWS + BR - 1) / BR + KREL)   // 4693
#define NB     (NTILES * BR)
#define TPB    4
#define MAXCHUNK ((NTILES + TPB - 1) / TPB + KREL)
#define NBH    ((N_ROWS + 255) / 256)            // 1172 histogram blocks

typedef __attribute__((ext_vector_type(8))) short bf8_t;   // 8 bf16 = 4 VGPR
typedef __attribute__((ext_vector_type(4))) float f32x4;
typedef __attribute__((ext_vector_type(4))) unsigned int u32x4;

static __device__ __forceinline__ unsigned pk2(float lo, float hi) {
  __hip_bfloat162 h = __float22bfloat162_rn(make_float2(lo, hi));
  return *reinterpret_cast<unsigned*>(&h);
}

static __device__ __forceinline__ bf8_t cvt8(float4 a, float4 b) {
  u32x4 u;
  u.x = pk2(a.x, a.y);
  u.y = pk2(a.z, a.w);
  u.z = pk2(b.x, b.y);
  u.w = pk2(b.z, b.w);
  return __builtin_bit_cast(bf8_t, u);
}

static __device__ __forceinline__ void stbf4_pk(void* base, int byte, float4 v) {
  unsigned long long p = (unsigned long long)pk2(v.x, v.y)
                       | ((unsigned long long)pk2(v.z, v.w) << 32);
  *(unsigned long long*)((char*)base + byte) = p;
}

static __device__ __forceinline__ bf8_t lds_load16(const void* base, int byte) {
  return *(const bf8_t*)((const char*)base + byte);
}

// ---------------- stable counting sort by relation ----------------
__global__ void blockhist_kernel(const int* __restrict__ r, int* __restrict__ blockcnt) {
  __shared__ int lc[KREL];
  int tid = threadIdx.x;
  if (tid < KREL) lc[tid] = 0;
  __syncthreads();
  int i = blockIdx.x * 256 + tid;
  if (i < N_ROWS) atomicAdd(&lc[r[i]], 1);
  __syncthreads();
  if (tid < KREL) blockcnt[blockIdx.x * KREL + tid] = lc[tid];
}

__global__ void scan_kernel(const int* __restrict__ blockcnt, int* __restrict__ base,
                            int* __restrict__ aoff, int* __restrict__ cb,
                            int* __restrict__ ts) {
  __shared__ int totals[KREL];
  __shared__ int aoff_s[KREL + 1];
  const int tid  = threadIdx.x;
  const int k    = tid >> 6;
  const int lane = tid & 63;

  if (k < KREL) {
    int part = 0;
    for (int b = lane; b < NBH; b += 64) part += blockcnt[b * KREL + k];
    #pragma unroll
    for (int off = 1; off < 64; off <<= 1) part += __shfl_xor(part, off);
    if (lane == 0) totals[k] = part;
  }
  __syncthreads();

  if (tid == 0) {
    int off = 0, cc = 0;
    for (int kk = 0; kk < KREL; ++kk) {
      aoff[kk] = off; aoff_s[kk] = off;
      off += ((totals[kk] + BR - 1) / BR) * BR;
    }
    aoff[KREL] = off; aoff_s[KREL] = off;
    for (int kk = 0; kk < KREL; ++kk) {
      ts[kk] = aoff_s[kk] / BR;
      int ntk = (aoff_s[kk + 1] - aoff_s[kk]) / BR;
      cb[kk] = cc;
      cc += (ntk + TPB - 1) / TPB;
    }
    cb[KREL] = cc;
    ts[KREL] = aoff_s[KREL] / BR;
  }
  __syncthreads();

  if (k < KREL) {
    int running = aoff_s[k];
    for (int b0 = 0; b0 < NBH; b0 += 64) {
      int b = b0 + lane;
      int v = (b < NBH) ? blockcnt[b * KREL + k] : 0;
      int s = v;
      #pragma unroll
      for (int off = 1; off < 64; off <<= 1) {
        int t = __shfl_up(s, off);
        if (lane >= off) s += t;
      }
      if (b < NBH) base[b * KREL + k] = running + s - v;
      running += __shfl(s, 63);
    }
  }
}

__global__ void scatter2_kernel(const int* __restrict__ r, const float* __restrict__ c,
                                const int* __restrict__ base, int* __restrict__ bucket,
                                float* __restrict__ cbv) {
  __shared__ int wcnt[4][KREL];
  __shared__ int wbase[4][KREL];
  const int tid  = threadIdx.x;
  const int wid  = tid >> 6;
  const int lane = tid & 63;
  const int i = blockIdx.x * 256 + tid;
  int k = -1; float cv = 0.f;
  if (i < N_ROWS) { k = r[i]; cv = c[i]; }

  int rank = 0;
  #pragma unroll
  for (int kk = 0; kk < KREL; ++kk) {
    unsigned long long m = __ballot(k == kk);
    if (lane == 0) wcnt[wid][kk] = __popcll(m);
    if (k == kk) rank = __popcll(m & ((1ull << lane) - 1ull));
  }
  __syncthreads();
  if (tid < KREL) {
    int b = base[blockIdx.x * KREL + tid];
    #pragma unroll
    for (int w = 0; w < 4; ++w) { wbase[w][tid] = b; b += wcnt[w][tid]; }
  }
  __syncthreads();
  if (i >= 0 && i < N_ROWS) {
    int pos = wbase[wid][k] + rank;
    bucket[pos] = i;
    cbv[pos]    = cv;
  }
}

// ---------------- main fused kernel ----------------
// R12 validated structure (single X buffer, same-wave in-order DS hazards,
// launch_bounds(256,2) -> no spill at 76 VGPRs). Only change: TPB 8->4 so the
// grid (2366 blocks, 9.2/CU) can fill the LDS residency limit (5 blocks/CU)
// instead of being dispatch-starved at 4.6 blocks/CU average.

__global__ __launch_bounds__(256, 2) void gcn_main(
    const float* __restrict__ user, const float* __restrict__ item,
    const float* __restrict__ Wu, const float* __restrict__ bu,
    const float* __restrict__ Wv, const float* __restrict__ bv,
    const float* __restrict__ Wl, const float* __restrict__ bl,
    const int* __restrict__ bucket, const float* __restrict__ cbv,
    const int* __restrict__ cb, const int* __restrict__ ts,
    float* __restrict__ out)
{
  __shared__ __align__(16) unsigned short sW[HDIM * FIN];   // 16 KB bf16, swizzled
  __shared__ __align__(16) unsigned short sX[BR * FIN];     // 16 KB bf16 (single buffer)

  const int tid  = threadIdx.x;
  const int side = blockIdx.x & 1;            // 0: item->u_out, 1: user->v_out
  const int cid  = blockIdx.x >> 1;
  if (cid >= cb[KREL]) return;

  const int rel = (cid >= cb[1]) + (cid >= cb[2]) + (cid >= cb[3]) + (cid >= cb[4]);
  const int t_begin = ts[rel] + (cid - cb[rel]) * TPB;
  const int t_end   = (t_begin + TPB < ts[rel + 1]) ? t_begin + TPB : ts[rel + 1];

  const float* X  = side ? user : item;
  const float* Wk = side ? Wv : Wu;
  const float* bk = side ? bv : bu;

  const int lane = tid & 63;
  const int wid  = tid >> 6;        // wave 0..3; owns tile rows [wid*16, wid*16+16)
  const int lrow = lane & 15;
  const int lkg  = lane >> 4;
  const int sh   = lane >> 5;       // staging: which row of the lane's pair
  const int c4   = lane & 31;       // staging: float4 column (global col = c4*4)

  // stage relation weights -> bf16 LDS, XOR-swizzled (row stride 256 B)
  {
    const float4* w4 = (const float4*)(Wk + (size_t)rel * HDIM * FIN);
    #pragma unroll
    for (int it = 0; it < 8; ++it) {
      int f4  = it * 256 + tid;
      int row = f4 >> 5;
      int cc  = f4 & 31;
      int byte = (row * 256 + cc * 8) ^ ((row & 7) << 4);
      stbf4_pk(sW, byte, w4[f4]);
    }
  }

  // layer-2 weights + biases in registers
  bf8_t wl[2][2];
  #pragma unroll
  for (int n2 = 0; n2 < 2; ++n2)
    #pragma unroll
    for (int k2 = 0; k2 < 2; ++k2) {
      const float* p = Wl + (size_t)(n2 * 16 + lrow) * HDIM + k2 * 32 + lkg * 8;
      wl[n2][k2] = cvt8(*(const float4*)p, *(const float4*)(p + 4));
    }
  const float blv0 = bl[lrow];
  const float blv1 = bl[16 + lrow];
  float bfrag[4];
  #pragma unroll
  for (int n = 0; n < 4; ++n) bfrag[n] = bk[rel * HDIM + n * 16 + lrow];

  // wave-private index prefetch: lane covers rows wid*16 + it*2 + sh, it=0..7
  int idxA[8], idxB[8];
  {
    const int tB = (t_begin + 1 < t_end) ? t_begin + 1 : t_begin;
    #pragma unroll
    for (int it = 0; it < 8; ++it) {
      idxA[it] = bucket[t_begin * BR + wid * 16 + it * 2 + sh];
      idxB[it] = bucket[tB * BR + wid * 16 + it * 2 + sh];
    }
  }

  char* myX = (char*)sX + wid * 4096;   // this wave's private 16-row region

  // prologue: stage first tile into this wave's region
  #pragma unroll
  for (int it = 0; it < 8; ++it) {
    int idx  = idxA[it] < 0 ? 0 : idxA[it];
    float4 a = *(const float4*)(X + (size_t)idx * FIN + c4 * 4);
    int rl   = it * 2 + sh;       // local row 0..15
    int byte = (rl * 256 + c4 * 8) ^ ((rl & 7) << 4);
    stbf4_pk(myX, byte, a);
  }
  __syncthreads();   // sW visible to all waves; ONLY barrier in the kernel

  for (int t = t_begin; t < t_end; ++t) {
    const int tile0 = t * BR;
    const bool do_stage = (t + 1 < t_end);

    // 1. issue index prefetch for t+2 (used as idxB next iteration)
    int idxC[8];
    {
      const int tC = (t + 2 < t_end) ? t + 2 : t;
      #pragma unroll
      for (int it = 0; it < 8; ++it)
        idxC[it] = bucket[tC * BR + wid * 16 + it * 2 + sh];
    }

    // 2. issue-early: gather loads for tile t+1 (write-late after compute)
    float4 ld[8];
    if (do_stage) {
      #pragma unroll
      for (int it = 0; it < 8; ++it) {
        int idx = idxB[it] < 0 ? 0 : idxB[it];
        ld[it]  = *(const float4*)(X + (size_t)idx * FIN + c4 * 4);
      }
    }

    // 3. epilogue inputs (coalesced)
    const int erow = tile0 + wid * 16 + lkg * 4;
    int4   idxQ4 = *(const int4*)(bucket + erow);
    float4 cQ4   = *(const float4*)(cbv + erow);
    int   idxQ[4] = {idxQ4.x, idxQ4.y, idxQ4.z, idxQ4.w};
    float cQ[4]   = {cQ4.x, cQ4.y, cQ4.z, cQ4.w};

    __builtin_amdgcn_sched_barrier(0);   // pin: loads above, compute below

    // 4. layer 1: [16 rows] x [64 h], K = 128 (A private, B shared W)
    f32x4 acc[4];
    #pragma unroll
    for (int n = 0; n < 4; ++n) acc[n] = f32x4{0.f, 0.f, 0.f, 0.f};

    const int axor = (lrow & 7) << 4;
    #pragma unroll
    for (int kc = 0; kc < 4; ++kc) {
      const int kb = (kc * 32 + lkg * 8) * 2;
      bf8_t au = lds_load16(myX, (lrow * 256 + kb) ^ axor);
      #pragma unroll
      for (int n = 0; n < 4; ++n) {
        int brow = n * 16 + lrow;
        int bx   = (brow * 256 + kb) ^ ((brow & 7) << 4);
        acc[n] = __builtin_amdgcn_mfma_f32_16x16x32_bf16(au, lds_load16(sW, bx), acc[n], 0, 0, 0);
      }
    }

    // 5. epilogue 1: H = relu(c*(acc+b)) -> bf16 into this wave's own region
    //    (after step-4 reads in program order; DS ops in-order per wave)
    #pragma unroll
    for (int n = 0; n < 4; ++n) {
      int hcol = n * 16 + lrow;
      #pragma unroll
      for (int q = 0; q < 4; ++q) {
        int rr   = lkg * 4 + q;      // local row 0..15
        int byte = (rr * 128 + hcol * 2) ^ ((rr & 7) << 4);
        float hv = fmaxf(cQ[q] * (acc[n][q] + bfrag[n]), 0.f);
        *(unsigned short*)(myX + byte) = (unsigned short)(pk2(hv, hv) & 0xFFFFu);
      }
    }

    // 6. layer 2: [16 rows] x [32 o], K = 64
    f32x4 acc2[2];
    acc2[0] = f32x4{0.f, 0.f, 0.f, 0.f};
    acc2[1] = f32x4{0.f, 0.f, 0.f, 0.f};
    #pragma unroll
    for (int k2 = 0; k2 < 2; ++k2) {
      const int kb = (k2 * 32 + lkg * 8) * 2;
      const int ax = (lrow * 128 + kb) ^ axor;
      bf8_t a2 = lds_load16(myX, ax);
      #pragma unroll
      for (int n2 = 0; n2 < 2; ++n2)
        acc2[n2] = __builtin_amdgcn_mfma_f32_16x16x32_bf16(a2, wl[n2][k2], acc2[n2], 0, 0, 0);
    }

    // 7. epilogue 2: out = relu(acc2 + bl), scattered row stores (retire async)
    const size_t obase = (size_t)side * N_ROWS * ODIM;
    #pragma unroll
    for (int n2 = 0; n2 < 2; ++n2) {
      int col  = n2 * 16 + lrow;
      float bb = (n2 == 0) ? blv0 : blv1;
      #pragma unroll
      for (int q = 0; q < 4; ++q) {
        int idx = idxQ[q];
        if (idx >= 0)
          out[obase + (size_t)idx * ODIM + col] = fmaxf(acc2[n2][q] + bb, 0.f);
      }
    }

    __builtin_amdgcn_sched_barrier(0);   // pin: staged writes stay below compute

    // 8. write-late: convert + ds_write tile t+1 into the SAME region
    //    (follows this wave's tile-t reads in program order; safe)
    if (do_stage) {
      #pragma unroll
      for (int it = 0; it < 8; ++it) {
        int rl   = it * 2 + sh;
        int byte = (rl * 256 + c4 * 8) ^ ((rl & 7) << 4);
        stbf4_pk(myX, byte, ld[it]);
      }
    }

    // 9. rotate index prefetch
    #pragma unroll
    for (int it = 0; it < 8; ++it) idxB[it] = idxC[it];
  }
}

extern "C" void kernel_launch(void* const* d_in, const int* in_sizes, int n_in,
                              void* d_out, int out_size, void* d_ws, size_t ws_size,
                              hipStream_t stream) {
  const float* user = (const float*)d_in[0];
  const float* item = (const float*)d_in[1];
  const int*   r    = (const int*)d_in[2];
  const float* c    = (const float*)d_in[3];
  const float* Wu   = (const float*)d_in[4];
  const float* bu   = (const float*)d_in[5];
  const float* Wv   = (const float*)d_in[6];
  const float* bv   = (const float*)d_in[7];
  const float* Wl   = (const float*)d_in[8];
  const float* bl   = (const float*)d_in[9];
  float* out = (float*)d_out;

  int*   bucket   = (int*)d_ws;              // NB
  float* cbv      = (float*)(bucket + NB);   // NB
  int*   blockcnt = (int*)(cbv + NB);        // NBH*KREL
  int*   base     = blockcnt + NBH * KREL;   // NBH*KREL
  int*   aoff     = base + NBH * KREL;       // KREL+1
  int*   cb       = aoff + KREL + 1;         // KREL+1
  int*   tsarr    = cb + KREL + 1;           // KREL+1

  hipMemsetAsync(bucket, 0xFF, (size_t)NB * sizeof(int), stream);
  hipMemsetAsync(cbv, 0, (size_t)NB * sizeof(float), stream);

  blockhist_kernel<<<NBH, 256, 0, stream>>>(r, blockcnt);
  scan_kernel<<<1, 320, 0, stream>>>(blockcnt, base, aoff, cb, tsarr);
  scatter2_kernel<<<NBH, 256, 0, stream>>>(r, c, base, bucket, cbv);
  gcn_main<<<2 * MAXCHUNK, 256, 0, stream>>>(user, item, Wu, bu, Wv, bv, Wl, bl,
                                             bucket, cbv, cb, tsarr, out);
}

// Round 14
// 113.276 us; speedup vs baseline: 1.0549x; 1.0549x over previous
//
#include <hip/hip_runtime.h>
#include <hip/hip_bf16.h>

#define N_ROWS 300000
#define FIN    128
#define HDIM   64
#define ODIM   32
#define KREL   5
#define BRT    128                                // rows per tile (8 waves x 16)
#define NTT    ((N_ROWS + BRT - 1) / BRT)         // 2344 tiles (last partial: 96 rows)
#define TPB    4
#define NCHUNK ((NTT + TPB - 1) / TPB)            // 586

typedef __attribute__((ext_vector_type(8))) short bf8_t;   // 8 bf16 = 4 VGPR
typedef __attribute__((ext_vector_type(4))) float f32x4;
typedef __attribute__((ext_vector_type(4))) unsigned int u32x4;

static __device__ __forceinline__ unsigned pk2(float lo, float hi) {
  __hip_bfloat162 h = __float22bfloat162_rn(make_float2(lo, hi));
  return *reinterpret_cast<unsigned*>(&h);
}

static __device__ __forceinline__ bf8_t cvt8(float4 a, float4 b) {
  u32x4 u;
  u.x = pk2(a.x, a.y);
  u.y = pk2(a.z, a.w);
  u.z = pk2(b.x, b.y);
  u.w = pk2(b.z, b.w);
  return __builtin_bit_cast(bf8_t, u);
}

static __device__ __forceinline__ void stbf4_pk(void* base, int byte, float4 v) {
  unsigned long long p = (unsigned long long)pk2(v.x, v.y)
                       | ((unsigned long long)pk2(v.z, v.w) << 32);
  *(unsigned long long*)((char*)base + byte) = p;
}

static __device__ __forceinline__ bf8_t lds_load16(const void* base, int byte) {
  return *(const bf8_t*)((const char*)base + byte);
}

// ---------------- single fused streaming kernel ----------------
// One block = one side x TPB tiles of 128 CONTIGUOUS rows. 512 threads =
// 8 waves, each owns 16 rows (wave-private X region; R12's proven single
// buffer with issue-early/write-late and same-wave in-order DS hazards; no
// in-loop barrier). All 5 relation weights live in LDS; per-row relation
// handled by masked-A MFMA: auk = (r[row]==k ? au : 0), acc summed over k.
// No sort, no gather, no scatter: X reads and out writes are streaming.
// LDS: 80KB W + 32KB X + 1.25KB bias = ~114KB -> 1 block/CU (8 waves).

__global__ __launch_bounds__(512, 1) void gcn_main(
    const float* __restrict__ user, const float* __restrict__ item,
    const int* __restrict__ r, const float* __restrict__ c,
    const float* __restrict__ Wu, const float* __restrict__ bu,
    const float* __restrict__ Wv, const float* __restrict__ bv,
    const float* __restrict__ Wl, const float* __restrict__ bl,
    float* __restrict__ out)
{
  __shared__ __align__(16) unsigned short sW[KREL * HDIM * FIN];  // 80 KB bf16, swizzled
  __shared__ __align__(16) unsigned short sX[BRT * FIN];          // 32 KB bf16, swizzled
  __shared__ float sB[KREL * HDIM];                               // 1.25 KB

  const int tid   = threadIdx.x;
  const int side  = blockIdx.x & 1;           // 0: item->u_out, 1: user->v_out
  const int chunk = blockIdx.x >> 1;
  const int t_begin = chunk * TPB;
  if (t_begin >= NTT) return;
  const int t_end = (t_begin + TPB < NTT) ? t_begin + TPB : NTT;

  const float* X  = side ? user : item;
  const float* Wk = side ? Wv : Wu;
  const float* bk = side ? bv : bu;

  const int lane = tid & 63;
  const int wid  = tid >> 6;        // wave 0..7; owns tile rows [wid*16, wid*16+16)
  const int lrow = lane & 15;
  const int lkg  = lane >> 4;
  const int sh   = lane >> 5;       // staging: which row of the lane's pair
  const int c4   = lane & 31;       // staging: float4 column

  // stage ALL 5 relation weights -> bf16 LDS, XOR-swizzled (16KB per relation)
  {
    const float4* w4 = (const float4*)Wk;     // [5][64][128] f32 contiguous
    #pragma unroll
    for (int j = 0; j < 20; ++j) {
      int f4   = j * 512 + tid;               // 0..10239
      int k    = f4 >> 11;                    // 2048 float4 per relation
      int rowk = (f4 >> 5) & 63;
      int cc   = f4 & 31;
      int byte = (k << 14) + ((rowk * 256 + cc * 8) ^ ((rowk & 7) << 4));
      stbf4_pk(sW, byte, w4[f4]);
    }
  }
  if (tid < KREL * HDIM) sB[tid] = bk[tid];

  // layer-2 weights + biases in registers
  bf8_t wl[2][2];
  #pragma unroll
  for (int n2 = 0; n2 < 2; ++n2)
    #pragma unroll
    for (int k2 = 0; k2 < 2; ++k2) {
      const float* p = Wl + (size_t)(n2 * 16 + lrow) * HDIM + k2 * 32 + lkg * 8;
      wl[n2][k2] = cvt8(*(const float4*)p, *(const float4*)(p + 4));
    }
  const float blv0 = bl[lrow];
  const float blv1 = bl[16 + lrow];

  char* myX = (char*)sX + wid * 4096;   // this wave's private 16-row region
  const int rowb_off = wid * 16;

  // prologue: stage first tile (contiguous rows, clamped at N)
  #pragma unroll
  for (int it = 0; it < 8; ++it) {
    int grow = t_begin * BRT + rowb_off + it * 2 + sh;
    grow = (grow < N_ROWS) ? grow : N_ROWS - 1;
    float4 a = *(const float4*)(X + (size_t)grow * FIN + c4 * 4);
    int rl   = it * 2 + sh;
    int byte = (rl * 256 + c4 * 8) ^ ((rl & 7) << 4);
    stbf4_pk(myX, byte, a);
  }
  __syncthreads();   // sW/sB visible; ONLY barrier in the kernel

  for (int t = t_begin; t < t_end; ++t) {
    const int tile0 = t * BRT;
    const bool do_stage = (t + 1 < t_end);

    // A-row relation for this lane (row = tile0 + wid*16 + lrow)
    int rowA = tile0 + rowb_off + lrow;
    int myrel = r[(rowA < N_ROWS) ? rowA : N_ROWS - 1];

    // issue-early: streaming loads of tile t+1's rows (write-late below)
    float4 ld[8];
    if (do_stage) {
      #pragma unroll
      for (int it = 0; it < 8; ++it) {
        int grow = tile0 + BRT + rowb_off + it * 2 + sh;
        grow = (grow < N_ROWS) ? grow : N_ROWS - 1;
        ld[it] = *(const float4*)(X + (size_t)grow * FIN + c4 * 4);
      }
    }

    // epilogue inputs (natural order; clamped)
    const int erow = tile0 + rowb_off + lkg * 4;
    int rQ[4]; float cQ[4];
    #pragma unroll
    for (int q = 0; q < 4; ++q) {
      int rc = erow + q;
      rc = (rc < N_ROWS) ? rc : N_ROWS - 1;
      rQ[q] = r[rc];
      cQ[q] = c[rc];
    }

    __builtin_amdgcn_sched_barrier(0);   // pin: loads above, compute below

    // layer 1: 5-relation masked accumulation, K = 128
    f32x4 acc[4];
    #pragma unroll
    for (int n = 0; n < 4; ++n) acc[n] = f32x4{0.f, 0.f, 0.f, 0.f};

    const bf8_t zero8 = {};
    const int axor = (lrow & 7) << 4;
    #pragma unroll
    for (int kc = 0; kc < 4; ++kc) {
      const int kb = (kc * 32 + lkg * 8) * 2;
      bf8_t au = lds_load16(myX, (lrow * 256 + kb) ^ axor);
      #pragma unroll
      for (int k = 0; k < KREL; ++k) {
        bf8_t auk = (myrel == k) ? au : zero8;     // 4 v_cndmask
        const int kofs = k << 14;
        #pragma unroll
        for (int n = 0; n < 4; ++n) {
          int brow = n * 16 + lrow;
          int bx   = kofs + ((brow * 256 + kb) ^ ((brow & 7) << 4));
          acc[n] = __builtin_amdgcn_mfma_f32_16x16x32_bf16(auk, lds_load16(sW, bx), acc[n], 0, 0, 0);
        }
      }
    }

    // epilogue 1: H = relu(c*(acc + b[rel])) -> bf16 into this wave's region
    #pragma unroll
    for (int n = 0; n < 4; ++n) {
      int hcol = n * 16 + lrow;
      #pragma unroll
      for (int q = 0; q < 4; ++q) {
        int rr   = lkg * 4 + q;      // local row 0..15
        int byte = (rr * 128 + hcol * 2) ^ ((rr & 7) << 4);
        float bb = sB[rQ[q] * HDIM + hcol];
        float hv = fmaxf(cQ[q] * (acc[n][q] + bb), 0.f);
        *(unsigned short*)(myX + byte) = (unsigned short)(pk2(hv, hv) & 0xFFFFu);
      }
    }

    // layer 2: [16 rows] x [32 o], K = 64 (same-wave LDS RAW; no barrier)
    f32x4 acc2[2];
    acc2[0] = f32x4{0.f, 0.f, 0.f, 0.f};
    acc2[1] = f32x4{0.f, 0.f, 0.f, 0.f};
    #pragma unroll
    for (int k2 = 0; k2 < 2; ++k2) {
      const int kb = (k2 * 32 + lkg * 8) * 2;
      const int ax = (lrow * 128 + kb) ^ axor;
      bf8_t a2 = lds_load16(myX, ax);
      #pragma unroll
      for (int n2 = 0; n2 < 2; ++n2)
        acc2[n2] = __builtin_amdgcn_mfma_f32_16x16x32_bf16(a2, wl[n2][k2], acc2[n2], 0, 0, 0);
    }

    // epilogue 2: out = relu(acc2 + bl), NATURAL-ORDER coalesced stores
    const size_t obase = (size_t)side * N_ROWS * ODIM;
    #pragma unroll
    for (int n2 = 0; n2 < 2; ++n2) {
      int col  = n2 * 16 + lrow;
      float bb = (n2 == 0) ? blv0 : blv1;
      #pragma unroll
      for (int q = 0; q < 4; ++q) {
        int row = erow + q;
        if (row < N_ROWS)
          out[obase + (size_t)row * ODIM + col] = fmaxf(acc2[n2][q] + bb, 0.f);
      }
    }

    __builtin_amdgcn_sched_barrier(0);   // pin: staged writes stay below compute

    // write-late: convert + ds_write tile t+1 into the SAME wave-private region
    if (do_stage) {
      #pragma unroll
      for (int it = 0; it < 8; ++it) {
        int rl   = it * 2 + sh;
        int byte = (rl * 256 + c4 * 8) ^ ((rl & 7) << 4);
        stbf4_pk(myX, byte, ld[it]);
      }
    }
  }
}

extern "C" void kernel_launch(void* const* d_in, const int* in_sizes, int n_in,
                              void* d_out, int out_size, void* d_ws, size_t ws_size,
                              hipStream_t stream) {
  const float* user = (const float*)d_in[0];
  const float* item = (const float*)d_in[1];
  const int*   r    = (const int*)d_in[2];
  const float* c    = (const float*)d_in[3];
  const float* Wu   = (const float*)d_in[4];
  const float* bu   = (const float*)d_in[5];
  const float* Wv   = (const float*)d_in[6];
  const float* bv   = (const float*)d_in[7];
  const float* Wl   = (const float*)d_in[8];
  const float* bl   = (const float*)d_in[9];
  float* out = (float*)d_out;

  gcn_main<<<2 * NCHUNK, 512, 0, stream>>>(user, item, r, c, Wu, bu, Wv, bv,
                                           Wl, bl, out);
}